// Round 10
// baseline (507.801 us; speedup 1.0000x reference)
//
#include <hip/hip_runtime.h>
#include <hip/hip_bf16.h>

#define NN 20000
#define DEG 16
#define KD 512      // IN_DIM
#define OD 512      // OUT_DIM
#define NH 4
#define DH 128
#define DROPE 126

#define BM 128
#define BN 128
#define BK 32       // [128][32] tiles (4 chunks/row), XOR-swizzled, global_load_lds

typedef unsigned short u16;
typedef unsigned int u32;
typedef __attribute__((ext_vector_type(8))) short short8;
typedef __attribute__((ext_vector_type(4))) float f32x4;

__device__ __forceinline__ float b2f(u16 u){ return __uint_as_float((u32)u << 16); }
__device__ __forceinline__ u16 f2b(float f){
  u32 x = __float_as_uint(f);
  return (u16)((x + 0x7fffu + ((x >> 16) & 1u)) >> 16);   // RNE
}
__device__ __forceinline__ void up8(uint4 u, float* f){
  f[0]=__uint_as_float(u.x<<16); f[1]=__uint_as_float(u.x&0xffff0000u);
  f[2]=__uint_as_float(u.y<<16); f[3]=__uint_as_float(u.y&0xffff0000u);
  f[4]=__uint_as_float(u.z<<16); f[5]=__uint_as_float(u.z&0xffff0000u);
  f[6]=__uint_as_float(u.w<<16); f[7]=__uint_as_float(u.w&0xffff0000u);
}
__device__ __forceinline__ uint4 cvt8(const float* s){
  uint4 a = *(const uint4*)s;
  uint4 b = *(const uint4*)(s + 4);
  uint4 o;
  o.x = (u32)f2b(__uint_as_float(a.x)) | ((u32)f2b(__uint_as_float(a.y)) << 16);
  o.y = (u32)f2b(__uint_as_float(a.z)) | ((u32)f2b(__uint_as_float(a.w)) << 16);
  o.z = (u32)f2b(__uint_as_float(b.x)) | ((u32)f2b(__uint_as_float(b.y)) << 16);
  o.w = (u32)f2b(__uint_as_float(b.z)) | ((u32)f2b(__uint_as_float(b.w)) << 16);
  return o;
}

// async global->LDS, 16B per lane; LDS dest is wave-uniform base + lane*16
__device__ __forceinline__ void load_lds16(const u16* g, u16* l) {
  __builtin_amdgcn_global_load_lds(
      (const __attribute__((address_space(1))) void*)g,
      (__attribute__((address_space(3))) void*)l, 16, 0, 0);
}

// single fused f32->bf16 conversion pass: x (5000 blocks), W x4 (512), biases (1)
struct ConvJob {
  const float* x;  u16* xb;                  // NN*KD
  const float* w[4]; u16* wb[4];             // OD*KD each
  const float* b[4]; u16* bb[4];             // OD each
};
__global__ __launch_bounds__(256) void conv_all(ConvJob j) {
  const int b = blockIdx.x;
  if (b < 5000) {                            // x: 10.24M elems
    const int i8 = (b * 256 + threadIdx.x) * 8;
    *(uint4*)(j.xb + i8) = cvt8(j.x + i8);
  } else if (b < 5512) {                     // weights: 4 x 262144 elems
    const int t = b - 5000;
    const int wsel = t >> 7;                 // 128 blocks per weight
    const int i8 = ((t & 127) * 256 + threadIdx.x) * 8;
    *(uint4*)(j.wb[wsel] + i8) = cvt8(j.w[wsel] + i8);
  } else {                                   // biases: 4 x 512 elems in one block
    const int vsel = threadIdx.x >> 6;
    const int i8 = (threadIdx.x & 63) * 8;
    *(uint4*)(j.bb[vsel] + i8) = cvt8(j.b[vsel] + i8);
  }
}

// out[m][o] = sum_k A[m][k]*W[o][k] + bias[o]
// mode 0: q -> scale + rope -> o0 [N][H][DH] bf16
// mode 1: k -> rope -> o1 [N][H][DH] bf16
// mode 2: natural store to o2 [M][OD]  (f32 iff f32out, else bf16)
// BK=32 + two-pass epilogue repack -> LDS ~20KB -> 7-8 blocks/CU (was 4):
// barrier-drain overlap comes from co-resident blocks (m114 mechanism).
__global__ __launch_bounds__(256, 6) void gemm_k(
    const u16* __restrict__ A,
    const u16* __restrict__ W0, const u16* __restrict__ B0,
    const u16* __restrict__ W1, const u16* __restrict__ B1,
    const u16* __restrict__ W2, const u16* __restrict__ B2,
    const float* __restrict__ pos,          // f32! bf16 pos loses 0.2 rad of RoPE angle
    u16* __restrict__ o0, u16* __restrict__ o1, void* __restrict__ o2,
    int M, int only2, int f32out)
{
  // union: staging (As 8KB + Bs 8KB) / epilogue half-tile repack (<=18.4KB)
  __shared__ __align__(16) char smem[18432];
  __shared__ float posS[BM*3];
  __shared__ float freqS[21];               // 10000^(-m/21), m=0..20
  u16* As = (u16*)smem;               // [128 rows][4 chunks], chunk XOR-swizzled
  u16* Bs = As + BM*BK;               // byte offset 8192

  const int b = blockIdx.x;
  const int xcd = b & 7, rem = b >> 3;
  int rowT, colT, w;
  if (only2) {
    rowT = (rem >> 2)*8 + xcd; colT = rem & 3; w = 2;
  } else {
    rowT = (rem / 12)*8 + xcd; const int sub = rem % 12; colT = sub & 3; w = sub >> 2;
  }
  if (rowT*BM >= M) return;

  const int tid = threadIdx.x;
  const int wave = tid >> 6, lane = tid & 63;
  const int wr = wave >> 1, wc = wave & 1;
  const int lm = lane & 15, lq = lane >> 4;
  const u16* W  = (w == 0) ? W0 : ((w == 1) ? W1 : W2);
  const u16* Bi = (w == 0) ? B0 : ((w == 1) ? B1 : B2);
  const int mode = w;                 // uniform per block
  u16* outQK = (w == 0) ? o0 : o1;

  f32x4 acc[4][4];
  #pragma unroll
  for (int i = 0; i < 4; i++)
    #pragma unroll
    for (int jj = 0; jj < 4; jj++)
      acc[i][jj] = (f32x4){0.f, 0.f, 0.f, 0.f};

  if (mode < 2) {                     // stage pos + freq (covered by first barrier)
    if (tid < BM) {
      int gr = rowT*BM + tid; if (gr >= M) gr = M - 1;
      posS[tid*3+0] = pos[gr*3+0];
      posS[tid*3+1] = pos[gr*3+1];
      posS[tid*3+2] = pos[gr*3+2];
    }
    if (tid >= BM && tid < BM + 21)
      freqS[tid - BM] = __expf(-(float)(tid - BM) * 0.43858763676077064f);
  }

  for (int kt = 0; kt < KD; kt += BK) {
    // stage A/B: 512 16B-chunks per tile / 256 threads = 2 iters each.
    // physical chunk c = row*4 + s holds global seg (s ^ (row&3));
    // consumer ds_read (row, k-seg lq) -> slot lq^(row&3): 8 lanes/bank-pos.
    #pragma unroll
    for (int it = 0; it < 2; it++) {
      const int chunk = it*256 + wave*64 + lane;   // 0..511
      const int row = chunk >> 2, gseg = (chunk & 3) ^ (row & 3);
      int gr = rowT*BM + row; if (gr >= M) gr = M - 1;
      load_lds16(A + (size_t)gr*KD + kt + gseg*8,
                 As + (size_t)(it*256 + wave*64)*8);
    }
    #pragma unroll
    for (int it = 0; it < 2; it++) {
      const int chunk = it*256 + wave*64 + lane;
      const int row = chunk >> 2, gseg = (chunk & 3) ^ (row & 3);
      load_lds16(W + (size_t)(colT*BN + row)*KD + kt + gseg*8,
                 Bs + (size_t)(it*256 + wave*64)*8);
    }
    __syncthreads();                  // drains vmcnt (global_load_lds) too
    short8 af[4], bfr[4];
    #pragma unroll
    for (int i = 0; i < 4; i++) {
      const int ra = wr*64 + i*16 + lm;
      af[i] = *(const short8*)(As + (size_t)(ra*4 + (lq ^ (ra & 3)))*8);
    }
    #pragma unroll
    for (int i = 0; i < 4; i++) {
      const int rb = wc*64 + i*16 + lm;
      bfr[i] = *(const short8*)(Bs + (size_t)(rb*4 + (lq ^ (rb & 3)))*8);
    }
    #pragma unroll
    for (int mi = 0; mi < 4; mi++)
      #pragma unroll
      for (int ni = 0; ni < 4; ni++)
        acc[mi][ni] = __builtin_amdgcn_mfma_f32_16x16x32_bf16(af[mi], bfr[ni], acc[mi][ni], 0, 0, 0);
    __syncthreads();
  }

  float bvv[4];
  #pragma unroll
  for (int ni = 0; ni < 4; ni++)
    bvv[ni] = b2f(Bi[colT*BN + wc*64 + ni*16 + lm]);

  u16* Cs = (u16*)smem;   // tiles dead after final barrier

  if (mode == 2 && f32out) {
    // direct f32 stores (payload 64KB > LDS); 64B segments per lq-group
    #pragma unroll
    for (int mi = 0; mi < 4; mi++)
      #pragma unroll
      for (int ni = 0; ni < 4; ni++) {
        const int Cg = colT*BN + wc*64 + ni*16 + lm;
        #pragma unroll
        for (int r = 0; r < 4; r++) {
          const int grow = rowT*BM + wr*64 + mi*16 + lq*4 + r;
          if (grow < M) ((float*)o2)[(size_t)grow*OD + Cg] = acc[mi][ni][r] + bvv[ni];
        }
      }
    return;
  }

  if (mode == 2) {
    // natural bf16 via 2-pass LDS repack: Cs [64 rows][136]
    #pragma unroll
    for (int pass = 0; pass < 2; pass++) {
      if (wr == pass) {               // wave-uniform: rows pass*64..+63
        #pragma unroll
        for (int mi = 0; mi < 4; mi++)
          #pragma unroll
          for (int ni = 0; ni < 4; ni++) {
            const int cloc = wc*64 + ni*16 + lm;
            #pragma unroll
            for (int r = 0; r < 4; r++) {
              const int rl = mi*16 + lq*4 + r;      // 0..63
              Cs[rl*136 + cloc] = f2b(acc[mi][ni][r] + bvv[ni]);
            }
          }
      }
      __syncthreads();
      #pragma unroll
      for (int sp = 0; sp < 4; sp++) {
        const int c2 = sp*256 + tid;          // 0..1023
        const int cc = c2 & 15, rl = c2 >> 4; // 16 chunks of 8 cols x 64 rows
        const int grow = rowT*BM + pass*64 + rl;
        if (grow < M) {
          uint4 v = *(const uint4*)(Cs + rl*136 + cc*8);
          *(uint4*)((u16*)o2 + (size_t)grow*OD + colT*BN + cc*8) = v;
        }
      }
      __syncthreads();                // WAR before next pass
    }
    return;
  }

  // modes 0/1: scale/rope then 2-pass repack to head-major [N][4][128]
  // Cs layout per pass: [rl 64][h 4][dloc 36(pad)]
  #pragma unroll
  for (int pass = 0; pass < 2; pass++) {
    if (wr == pass) {
      #pragma unroll
      for (int mi = 0; mi < 4; mi++) {
        #pragma unroll
        for (int ni = 0; ni < 4; ni++) {
          const int cloc = wc*64 + ni*16 + lm;
          const int h = cloc & 3, dloc = cloc >> 2;
          const int d = colT*32 + dloc;
          #pragma unroll
          for (int r = 0; r < 4; r++) {
            const int rl = mi*16 + lq*4 + r;        // 0..63
            const int rloc = pass*64 + rl;          // global row in tile
            float v = acc[mi][ni][r] + bvv[ni];
            if (mode == 0) v *= 0.08838834764831845f;   // 1/sqrt(128)
            const float partner = __shfl_xor(v, 4);     // rope pair: d ^ 1 == lane ^ 4
            float vr = v;
            if (d < DROPE) {
              const int pp = d / 42, rem2 = d - pp*42, m = rem2 >> 1, par = rem2 & 1;
              const float ang = posS[rloc*3 + pp] * freqS[m];
              float sn, cs; __sincosf(ang, &sn, &cs);
              vr = par ? (v*cs + partner*sn) : (v*cs - partner*sn);
            }
            Cs[rl*144 + h*36 + dloc] = f2b(vr);
          }
        }
      }
    }
    __syncthreads();
    #pragma unroll
    for (int sp = 0; sp < 4; sp++) {
      const int c2 = sp*256 + tid;              // 0..1023
      const int dd8 = c2 & 3, h = (c2 >> 2) & 3, rl = c2 >> 4;  // rl 0..63
      const int grow = rowT*BM + pass*64 + rl;
      if (grow < M) {
        uint2 a = *(const uint2*)(Cs + rl*144 + h*36 + dd8*8);
        uint2 b2 = *(const uint2*)(Cs + rl*144 + h*36 + dd8*8 + 4);
        *(uint4*)(outQK + ((size_t)grow*NH + h)*DH + colT*32 + dd8*8)
            = make_uint4(a.x, a.y, b2.x, b2.y);
      }
    }
    __syncthreads();                  // WAR before next pass
  }
}

// one wave per node. Coalesced per-neighbor row loads; lane l holds slice
// (h=l>>4, d=(l&15)*8) of q and k -> partial dot + h-group reduction.
// Plain (L1-allocating) loads: L1 coalesces the 4 lanes/line; nt-bypass
// quadrupled L2 requests and regressed (R9). At roofline: ~330MB compulsory
// per-XCD refill @ ~3.6TB/s fabric = ~90us.
__global__ __launch_bounds__(256, 3) void edge_attn(
    const int* __restrict__ cols, const u16* __restrict__ qf,
    const u16* __restrict__ kf, const u16* __restrict__ vf,
    u16* __restrict__ y)
{
  const int wave = threadIdx.x >> 6;
  const int lane = threadIdx.x & 63;
  const int n = blockIdx.x*4 + wave;
  const int j = lane >> 2, h = lane & 3;      // score layout
  const int col = cols[n*DEG + j];

  // own q slice (coalesced)
  const uint4 qall = *(const uint4*)(qf + (size_t)n*OD + lane*8);

  int cjs[16];
  #pragma unroll
  for (int jj = 0; jj < 16; jj++) cjs[jj] = __shfl(col, jj*4);

  // 16 coalesced k row loads (oldest first)
  uint4 kreg[16];
  #pragma unroll
  for (int jj = 0; jj < 16; jj++)
    kreg[jj] = *(const uint4*)(kf + (size_t)cjs[jj]*OD + lane*8);

  // 16 coalesced v row loads (stay in flight through the score phase)
  uint4 vreg[16];
  #pragma unroll
  for (int jj = 0; jj < 16; jj++)
    vreg[jj] = *(const uint4*)(vf + (size_t)cjs[jj]*OD + lane*8);

  float qa[8];
  up8(qall, qa);

  // scores
  float s = 0.f;
  #pragma unroll
  for (int jj = 0; jj < 16; jj++) {
    float ka[8];
    up8(kreg[jj], ka);
    float pr = qa[0]*ka[0] + qa[1]*ka[1] + qa[2]*ka[2] + qa[3]*ka[3]
             + qa[4]*ka[4] + qa[5]*ka[5] + qa[6]*ka[6] + qa[7]*ka[7];
    pr += __shfl_xor(pr, 1);
    pr += __shfl_xor(pr, 2);
    pr += __shfl_xor(pr, 4);
    pr += __shfl_xor(pr, 8);                 // all 16 lanes of h-group hold s[jj, hg]
    const float red = __shfl(pr, h*16);      // s[jj, h] from group h's lane 0
    s = (j == jj) ? red : s;
  }

  // softmax over j: lanes stride 4 share h; masks 4..32 never touch bits 0-1
  float mx = s;
  #pragma unroll
  for (int msk = 4; msk < 64; msk <<= 1) mx = fmaxf(mx, __shfl_xor(mx, msk));
  float p = expf(s - mx);
  float dn = p;
  #pragma unroll
  for (int msk = 4; msk < 64; msk <<= 1) dn += __shfl_xor(dn, msk);
  const float attn = p / dn;

  // y accumulate from prefetched v: lane owns natural cols c = lane*8..+7 (h = t&3)
  float ya[8];
  #pragma unroll
  for (int t = 0; t < 8; t++) ya[t] = 0.f;
  #pragma unroll
  for (int jj = 0; jj < 16; jj++) {
    const float a0 = __shfl(attn, jj*4+0);
    const float a1 = __shfl(attn, jj*4+1);
    const float a2 = __shfl(attn, jj*4+2);
    const float a3 = __shfl(attn, jj*4+3);
    float va[8];
    up8(vreg[jj], va);
    ya[0] += a0*va[0]; ya[1] += a1*va[1]; ya[2] += a2*va[2]; ya[3] += a3*va[3];
    ya[4] += a0*va[4]; ya[5] += a1*va[5]; ya[6] += a2*va[6]; ya[7] += a3*va[7];
  }
  u32 pk[4];
  #pragma unroll
  for (int t = 0; t < 4; t++)
    pk[t] = (u32)f2b(ya[2*t]) | ((u32)f2b(ya[2*t+1]) << 16);
  *(uint4*)(y + (size_t)n*OD + lane*8) = make_uint4(pk[0], pk[1], pk[2], pk[3]);
}

extern "C" void kernel_launch(void* const* d_in, const int* in_sizes, int n_in,
                              void* d_out, int out_size, void* d_ws, size_t ws_size,
                              hipStream_t stream) {
  (void)in_sizes; (void)n_in; (void)out_size; (void)ws_size;
  const float* x   = (const float*)d_in[0];
  const float* pos = (const float*)d_in[1];
  // d_in[2] = rows: sorted repeat(arange(N), DEG) — structure used implicitly
  const int* cols = (const int*)d_in[3];
  const float* Wq = (const float*)d_in[4];
  const float* bq = (const float*)d_in[5];
  const float* Wk = (const float*)d_in[6];
  const float* bk = (const float*)d_in[7];
  const float* Wv = (const float*)d_in[8];
  const float* bv = (const float*)d_in[9];
  const float* Wo = (const float*)d_in[10];
  const float* bo = (const float*)d_in[11];

  char* ws = (char*)d_ws;
  size_t off = 0;
  auto carve = [&](size_t bytes) { char* p = ws + off; off += (bytes + 15) & ~(size_t)15; return p; };
  u16* xb   = (u16*)carve((size_t)NN*KD*2);
  u16* Wqb  = (u16*)carve((size_t)OD*KD*2);
  u16* Wkb  = (u16*)carve((size_t)OD*KD*2);
  u16* Wvb  = (u16*)carve((size_t)OD*KD*2);
  u16* Wob  = (u16*)carve((size_t)OD*OD*2);
  u16* bqb  = (u16*)carve((size_t)OD*2);
  u16* bkb  = (u16*)carve((size_t)OD*2);
  u16* bvb  = (u16*)carve((size_t)OD*2);
  u16* bob  = (u16*)carve((size_t)OD*2);
  u16* qf   = (u16*)carve((size_t)NN*OD*2);
  u16* kf   = (u16*)carve((size_t)NN*OD*2);
  u16* vf   = (u16*)carve((size_t)NN*OD*2);
  u16* y    = (u16*)carve((size_t)NN*OD*2);

  ConvJob cj;
  cj.x = x; cj.xb = xb;
  cj.w[0]=Wq; cj.w[1]=Wk; cj.w[2]=Wv; cj.w[3]=Wo;
  cj.wb[0]=Wqb; cj.wb[1]=Wkb; cj.wb[2]=Wvb; cj.wb[3]=Wob;
  cj.b[0]=bq; cj.b[1]=bk; cj.b[2]=bv; cj.b[3]=bo;
  cj.bb[0]=bqb; cj.bb[1]=bkb; cj.bb[2]=bvb; cj.bb[3]=bob;
  conv_all<<<dim3(5513), 256, 0, stream>>>(cj);

  // QKV: 8 xcd * 20 rowT-slots * 12 (colT,w) = 1920 blocks (36 early-return)
  gemm_k<<<dim3(1920), 256, 0, stream>>>(xb, Wqb, bqb, Wkb, bkb, Wvb, bvb, pos,
                                         qf, kf, (void*)vf, NN, 0, 0);
  edge_attn<<<dim3(NN/4), 256, 0, stream>>>(cols, qf, kf, vf, y);
  // out: 8 * 20 * 4 = 640 blocks
  gemm_k<<<dim3(640), 256, 0, stream>>>(y, Wqb, bqb, Wkb, bkb, Wob, bob, pos,
                                        qf, kf, d_out, NN, 1, 1);
}

// Round 11
// 271.236 us; speedup vs baseline: 1.8722x; 1.8722x over previous
//
#include <hip/hip_runtime.h>
#include <hip/hip_bf16.h>

#define NN 20000
#define DEG 16
#define KD 512      // IN_DIM
#define OD 512      // OUT_DIM
#define NH 4
#define DH 128
#define DROPE 126

#define BM 128
#define BN 128
#define BK 32       // [128][32] tiles (4 chunks/row), XOR-swizzled, global_load_lds

typedef unsigned short u16;
typedef unsigned int u32;
typedef __attribute__((ext_vector_type(8))) short short8;
typedef __attribute__((ext_vector_type(4))) float f32x4;

__device__ __forceinline__ float b2f(u16 u){ return __uint_as_float((u32)u << 16); }
__device__ __forceinline__ u16 f2b(float f){
  u32 x = __float_as_uint(f);
  return (u16)((x + 0x7fffu + ((x >> 16) & 1u)) >> 16);   // RNE
}
__device__ __forceinline__ void up8(uint4 u, float* f){
  f[0]=__uint_as_float(u.x<<16); f[1]=__uint_as_float(u.x&0xffff0000u);
  f[2]=__uint_as_float(u.y<<16); f[3]=__uint_as_float(u.y&0xffff0000u);
  f[4]=__uint_as_float(u.z<<16); f[5]=__uint_as_float(u.z&0xffff0000u);
  f[6]=__uint_as_float(u.w<<16); f[7]=__uint_as_float(u.w&0xffff0000u);
}
__device__ __forceinline__ uint4 cvt8(const float* s){
  uint4 a = *(const uint4*)s;
  uint4 b = *(const uint4*)(s + 4);
  uint4 o;
  o.x = (u32)f2b(__uint_as_float(a.x)) | ((u32)f2b(__uint_as_float(a.y)) << 16);
  o.y = (u32)f2b(__uint_as_float(a.z)) | ((u32)f2b(__uint_as_float(a.w)) << 16);
  o.z = (u32)f2b(__uint_as_float(b.x)) | ((u32)f2b(__uint_as_float(b.y)) << 16);
  o.w = (u32)f2b(__uint_as_float(b.z)) | ((u32)f2b(__uint_as_float(b.w)) << 16);
  return o;
}

// async global->LDS, 16B per lane; LDS dest is wave-uniform base + lane*16
__device__ __forceinline__ void load_lds16(const u16* g, u16* l) {
  __builtin_amdgcn_global_load_lds(
      (const __attribute__((address_space(1))) void*)g,
      (__attribute__((address_space(3))) void*)l, 16, 0, 0);
}

// single fused f32->bf16 conversion pass: x (5000 blocks), W x4 (512), biases (1)
struct ConvJob {
  const float* x;  u16* xb;                  // NN*KD
  const float* w[4]; u16* wb[4];             // OD*KD each
  const float* b[4]; u16* bb[4];             // OD each
};
__global__ __launch_bounds__(256) void conv_all(ConvJob j) {
  const int b = blockIdx.x;
  if (b < 5000) {                            // x: 10.24M elems
    const int i8 = (b * 256 + threadIdx.x) * 8;
    *(uint4*)(j.xb + i8) = cvt8(j.x + i8);
  } else if (b < 5512) {                     // weights: 4 x 262144 elems
    const int t = b - 5000;
    const int wsel = t >> 7;                 // 128 blocks per weight
    const int i8 = ((t & 127) * 256 + threadIdx.x) * 8;
    *(uint4*)(j.wb[wsel] + i8) = cvt8(j.w[wsel] + i8);
  } else {                                   // biases: 4 x 512 elems in one block
    const int vsel = threadIdx.x >> 6;
    const int i8 = (threadIdx.x & 63) * 8;
    *(uint4*)(j.bb[vsel] + i8) = cvt8(j.b[vsel] + i8);
  }
}

// out[m][o] = sum_k A[m][k]*W[o][k] + bias[o]
// mode 0: q -> scale + rope -> o0 [N][H][DH] bf16
// mode 1: k -> rope -> o1 [N][H][DH] bf16
// mode 2: natural store to o2 [M][OD]  (f32 iff f32out, else bf16)
// BK=32 + two-pass epilogue repack -> LDS ~20KB -> up to 8 blocks/CU.
// launch_bounds (256,4): (256,6) capped VGPR below the 64-reg accumulator
// and spilled acc to scratch (R10: WRITE_SIZE 60->679MB, 2.6x slower).
__global__ __launch_bounds__(256, 4) void gemm_k(
    const u16* __restrict__ A,
    const u16* __restrict__ W0, const u16* __restrict__ B0,
    const u16* __restrict__ W1, const u16* __restrict__ B1,
    const u16* __restrict__ W2, const u16* __restrict__ B2,
    const float* __restrict__ pos,          // f32! bf16 pos loses 0.2 rad of RoPE angle
    u16* __restrict__ o0, u16* __restrict__ o1, void* __restrict__ o2,
    int M, int only2, int f32out)
{
  // union: staging (As 8KB + Bs 8KB) / epilogue half-tile repack (<=18.4KB)
  __shared__ __align__(16) char smem[18432];
  __shared__ float posS[BM*3];
  __shared__ float freqS[21];               // 10000^(-m/21), m=0..20
  u16* As = (u16*)smem;               // [128 rows][4 chunks], chunk XOR-swizzled
  u16* Bs = As + BM*BK;               // byte offset 8192

  const int b = blockIdx.x;
  const int xcd = b & 7, rem = b >> 3;
  int rowT, colT, w;
  if (only2) {
    rowT = (rem >> 2)*8 + xcd; colT = rem & 3; w = 2;
  } else {
    rowT = (rem / 12)*8 + xcd; const int sub = rem % 12; colT = sub & 3; w = sub >> 2;
  }
  if (rowT*BM >= M) return;

  const int tid = threadIdx.x;
  const int wave = tid >> 6, lane = tid & 63;
  const int wr = wave >> 1, wc = wave & 1;
  const int lm = lane & 15, lq = lane >> 4;
  const u16* W  = (w == 0) ? W0 : ((w == 1) ? W1 : W2);
  const u16* Bi = (w == 0) ? B0 : ((w == 1) ? B1 : B2);
  const int mode = w;                 // uniform per block
  u16* outQK = (w == 0) ? o0 : o1;

  f32x4 acc[4][4];
  #pragma unroll
  for (int i = 0; i < 4; i++)
    #pragma unroll
    for (int jj = 0; jj < 4; jj++)
      acc[i][jj] = (f32x4){0.f, 0.f, 0.f, 0.f};

  if (mode < 2) {                     // stage pos + freq (covered by first barrier)
    if (tid < BM) {
      int gr = rowT*BM + tid; if (gr >= M) gr = M - 1;
      posS[tid*3+0] = pos[gr*3+0];
      posS[tid*3+1] = pos[gr*3+1];
      posS[tid*3+2] = pos[gr*3+2];
    }
    if (tid >= BM && tid < BM + 21)
      freqS[tid - BM] = __expf(-(float)(tid - BM) * 0.43858763676077064f);
  }

  for (int kt = 0; kt < KD; kt += BK) {
    // stage A/B: 512 16B-chunks per tile / 256 threads = 2 iters each.
    // physical chunk c = row*4 + s holds global seg (s ^ (row&3));
    // consumer ds_read (row, k-seg lq) -> slot lq^(row&3): balanced banks.
    #pragma unroll
    for (int it = 0; it < 2; it++) {
      const int chunk = it*256 + wave*64 + lane;   // 0..511
      const int row = chunk >> 2, gseg = (chunk & 3) ^ (row & 3);
      int gr = rowT*BM + row; if (gr >= M) gr = M - 1;
      load_lds16(A + (size_t)gr*KD + kt + gseg*8,
                 As + (size_t)(it*256 + wave*64)*8);
    }
    #pragma unroll
    for (int it = 0; it < 2; it++) {
      const int chunk = it*256 + wave*64 + lane;
      const int row = chunk >> 2, gseg = (chunk & 3) ^ (row & 3);
      load_lds16(W + (size_t)(colT*BN + row)*KD + kt + gseg*8,
                 Bs + (size_t)(it*256 + wave*64)*8);
    }
    __syncthreads();                  // drains vmcnt (global_load_lds) too
    short8 af[4], bfr[4];
    #pragma unroll
    for (int i = 0; i < 4; i++) {
      const int ra = wr*64 + i*16 + lm;
      af[i] = *(const short8*)(As + (size_t)(ra*4 + (lq ^ (ra & 3)))*8);
    }
    #pragma unroll
    for (int i = 0; i < 4; i++) {
      const int rb = wc*64 + i*16 + lm;
      bfr[i] = *(const short8*)(Bs + (size_t)(rb*4 + (lq ^ (rb & 3)))*8);
    }
    #pragma unroll
    for (int mi = 0; mi < 4; mi++)
      #pragma unroll
      for (int ni = 0; ni < 4; ni++)
        acc[mi][ni] = __builtin_amdgcn_mfma_f32_16x16x32_bf16(af[mi], bfr[ni], acc[mi][ni], 0, 0, 0);
    __syncthreads();
  }

  float bvv[4];
  #pragma unroll
  for (int ni = 0; ni < 4; ni++)
    bvv[ni] = b2f(Bi[colT*BN + wc*64 + ni*16 + lm]);

  u16* Cs = (u16*)smem;   // tiles dead after final barrier

  if (mode == 2 && f32out) {
    // direct f32 stores (payload 64KB > LDS); 64B segments per lq-group
    #pragma unroll
    for (int mi = 0; mi < 4; mi++)
      #pragma unroll
      for (int ni = 0; ni < 4; ni++) {
        const int Cg = colT*BN + wc*64 + ni*16 + lm;
        #pragma unroll
        for (int r = 0; r < 4; r++) {
          const int grow = rowT*BM + wr*64 + mi*16 + lq*4 + r;
          if (grow < M) ((float*)o2)[(size_t)grow*OD + Cg] = acc[mi][ni][r] + bvv[ni];
        }
      }
    return;
  }

  if (mode == 2) {
    // natural bf16 via 2-pass LDS repack: Cs [64 rows][136]
    #pragma unroll
    for (int pass = 0; pass < 2; pass++) {
      if (wr == pass) {               // wave-uniform: rows pass*64..+63
        #pragma unroll
        for (int mi = 0; mi < 4; mi++)
          #pragma unroll
          for (int ni = 0; ni < 4; ni++) {
            const int cloc = wc*64 + ni*16 + lm;
            #pragma unroll
            for (int r = 0; r < 4; r++) {
              const int rl = mi*16 + lq*4 + r;      // 0..63
              Cs[rl*136 + cloc] = f2b(acc[mi][ni][r] + bvv[ni]);
            }
          }
      }
      __syncthreads();
      #pragma unroll
      for (int sp = 0; sp < 4; sp++) {
        const int c2 = sp*256 + tid;          // 0..1023
        const int cc = c2 & 15, rl = c2 >> 4; // 16 chunks of 8 cols x 64 rows
        const int grow = rowT*BM + pass*64 + rl;
        if (grow < M) {
          uint4 v = *(const uint4*)(Cs + rl*136 + cc*8);
          *(uint4*)((u16*)o2 + (size_t)grow*OD + colT*BN + cc*8) = v;
        }
      }
      __syncthreads();                // WAR before next pass
    }
    return;
  }

  // modes 0/1: scale/rope then 2-pass repack to head-major [N][4][128]
  // Cs layout per pass: [rl 64][h 4][dloc 36(pad)]
  #pragma unroll
  for (int pass = 0; pass < 2; pass++) {
    if (wr == pass) {
      #pragma unroll
      for (int mi = 0; mi < 4; mi++) {
        #pragma unroll
        for (int ni = 0; ni < 4; ni++) {
          const int cloc = wc*64 + ni*16 + lm;
          const int h = cloc & 3, dloc = cloc >> 2;
          const int d = colT*32 + dloc;
          #pragma unroll
          for (int r = 0; r < 4; r++) {
            const int rl = mi*16 + lq*4 + r;        // 0..63
            const int rloc = pass*64 + rl;          // global row in tile
            float v = acc[mi][ni][r] + bvv[ni];
            if (mode == 0) v *= 0.08838834764831845f;   // 1/sqrt(128)
            const float partner = __shfl_xor(v, 4);     // rope pair: d ^ 1 == lane ^ 4
            float vr = v;
            if (d < DROPE) {
              const int pp = d / 42, rem2 = d - pp*42, m = rem2 >> 1, par = rem2 & 1;
              const float ang = posS[rloc*3 + pp] * freqS[m];
              float sn, cs; __sincosf(ang, &sn, &cs);
              vr = par ? (v*cs + partner*sn) : (v*cs - partner*sn);
            }
            Cs[rl*144 + h*36 + dloc] = f2b(vr);
          }
        }
      }
    }
    __syncthreads();
    #pragma unroll
    for (int sp = 0; sp < 4; sp++) {
      const int c2 = sp*256 + tid;              // 0..1023
      const int dd8 = c2 & 3, h = (c2 >> 2) & 3, rl = c2 >> 4;  // rl 0..63
      const int grow = rowT*BM + pass*64 + rl;
      if (grow < M) {
        uint2 a = *(const uint2*)(Cs + rl*144 + h*36 + dd8*8);
        uint2 b2 = *(const uint2*)(Cs + rl*144 + h*36 + dd8*8 + 4);
        *(uint4*)(outQK + ((size_t)grow*NH + h)*DH + colT*32 + dd8*8)
            = make_uint4(a.x, a.y, b2.x, b2.y);
      }
    }
    __syncthreads();                  // WAR before next pass
  }
}

// one wave per node. Coalesced per-neighbor row loads; lane l holds slice
// (h=l>>4, d=(l&15)*8) of q and k -> partial dot + h-group reduction.
// Plain (L1-allocating) loads: L1 coalesces the 4 lanes/line; nt-bypass
// quadrupled L2 requests and regressed (R9). At roofline: ~330MB compulsory
// per-XCD refill @ ~3.6TB/s fabric = ~90us.
__global__ __launch_bounds__(256, 3) void edge_attn(
    const int* __restrict__ cols, const u16* __restrict__ qf,
    const u16* __restrict__ kf, const u16* __restrict__ vf,
    u16* __restrict__ y)
{
  const int wave = threadIdx.x >> 6;
  const int lane = threadIdx.x & 63;
  const int n = blockIdx.x*4 + wave;
  const int j = lane >> 2, h = lane & 3;      // score layout
  const int col = cols[n*DEG + j];

  // own q slice (coalesced)
  const uint4 qall = *(const uint4*)(qf + (size_t)n*OD + lane*8);

  int cjs[16];
  #pragma unroll
  for (int jj = 0; jj < 16; jj++) cjs[jj] = __shfl(col, jj*4);

  // 16 coalesced k row loads (oldest first)
  uint4 kreg[16];
  #pragma unroll
  for (int jj = 0; jj < 16; jj++)
    kreg[jj] = *(const uint4*)(kf + (size_t)cjs[jj]*OD + lane*8);

  // 16 coalesced v row loads (stay in flight through the score phase)
  uint4 vreg[16];
  #pragma unroll
  for (int jj = 0; jj < 16; jj++)
    vreg[jj] = *(const uint4*)(vf + (size_t)cjs[jj]*OD + lane*8);

  float qa[8];
  up8(qall, qa);

  // scores
  float s = 0.f;
  #pragma unroll
  for (int jj = 0; jj < 16; jj++) {
    float ka[8];
    up8(kreg[jj], ka);
    float pr = qa[0]*ka[0] + qa[1]*ka[1] + qa[2]*ka[2] + qa[3]*ka[3]
             + qa[4]*ka[4] + qa[5]*ka[5] + qa[6]*ka[6] + qa[7]*ka[7];
    pr += __shfl_xor(pr, 1);
    pr += __shfl_xor(pr, 2);
    pr += __shfl_xor(pr, 4);
    pr += __shfl_xor(pr, 8);                 // all 16 lanes of h-group hold s[jj, hg]
    const float red = __shfl(pr, h*16);      // s[jj, h] from group h's lane 0
    s = (j == jj) ? red : s;
  }

  // softmax over j: lanes stride 4 share h; masks 4..32 never touch bits 0-1
  float mx = s;
  #pragma unroll
  for (int msk = 4; msk < 64; msk <<= 1) mx = fmaxf(mx, __shfl_xor(mx, msk));
  float p = expf(s - mx);
  float dn = p;
  #pragma unroll
  for (int msk = 4; msk < 64; msk <<= 1) dn += __shfl_xor(dn, msk);
  const float attn = p / dn;

  // y accumulate from prefetched v: lane owns natural cols c = lane*8..+7 (h = t&3)
  float ya[8];
  #pragma unroll
  for (int t = 0; t < 8; t++) ya[t] = 0.f;
  #pragma unroll
  for (int jj = 0; jj < 16; jj++) {
    const float a0 = __shfl(attn, jj*4+0);
    const float a1 = __shfl(attn, jj*4+1);
    const float a2 = __shfl(attn, jj*4+2);
    const float a3 = __shfl(attn, jj*4+3);
    float va[8];
    up8(vreg[jj], va);
    ya[0] += a0*va[0]; ya[1] += a1*va[1]; ya[2] += a2*va[2]; ya[3] += a3*va[3];
    ya[4] += a0*va[4]; ya[5] += a1*va[5]; ya[6] += a2*va[6]; ya[7] += a3*va[7];
  }
  u32 pk[4];
  #pragma unroll
  for (int t = 0; t < 4; t++)
    pk[t] = (u32)f2b(ya[2*t]) | ((u32)f2b(ya[2*t+1]) << 16);
  *(uint4*)(y + (size_t)n*OD + lane*8) = make_uint4(pk[0], pk[1], pk[2], pk[3]);
}

extern "C" void kernel_launch(void* const* d_in, const int* in_sizes, int n_in,
                              void* d_out, int out_size, void* d_ws, size_t ws_size,
                              hipStream_t stream) {
  (void)in_sizes; (void)n_in; (void)out_size; (void)ws_size;
  const float* x   = (const float*)d_in[0];
  const float* pos = (const float*)d_in[1];
  // d_in[2] = rows: sorted repeat(arange(N), DEG) — structure used implicitly
  const int* cols = (const int*)d_in[3];
  const float* Wq = (const float*)d_in[4];
  const float* bq = (const float*)d_in[5];
  const float* Wk = (const float*)d_in[6];
  const float* bk = (const float*)d_in[7];
  const float* Wv = (const float*)d_in[8];
  const float* bv = (const float*)d_in[9];
  const float* Wo = (const float*)d_in[10];
  const float* bo = (const float*)d_in[11];

  char* ws = (char*)d_ws;
  size_t off = 0;
  auto carve = [&](size_t bytes) { char* p = ws + off; off += (bytes + 15) & ~(size_t)15; return p; };
  u16* xb   = (u16*)carve((size_t)NN*KD*2);
  u16* Wqb  = (u16*)carve((size_t)OD*KD*2);
  u16* Wkb  = (u16*)carve((size_t)OD*KD*2);
  u16* Wvb  = (u16*)carve((size_t)OD*KD*2);
  u16* Wob  = (u16*)carve((size_t)OD*OD*2);
  u16* bqb  = (u16*)carve((size_t)OD*2);
  u16* bkb  = (u16*)carve((size_t)OD*2);
  u16* bvb  = (u16*)carve((size_t)OD*2);
  u16* bob  = (u16*)carve((size_t)OD*2);
  u16* qf   = (u16*)carve((size_t)NN*OD*2);
  u16* kf   = (u16*)carve((size_t)NN*OD*2);
  u16* vf   = (u16*)carve((size_t)NN*OD*2);
  u16* y    = (u16*)carve((size_t)NN*OD*2);

  ConvJob cj;
  cj.x = x; cj.xb = xb;
  cj.w[0]=Wq; cj.w[1]=Wk; cj.w[2]=Wv; cj.w[3]=Wo;
  cj.wb[0]=Wqb; cj.wb[1]=Wkb; cj.wb[2]=Wvb; cj.wb[3]=Wob;
  cj.b[0]=bq; cj.b[1]=bk; cj.b[2]=bv; cj.b[3]=bo;
  cj.bb[0]=bqb; cj.bb[1]=bkb; cj.bb[2]=bvb; cj.bb[3]=bob;
  conv_all<<<dim3(5513), 256, 0, stream>>>(cj);

  // QKV: 8 xcd * 20 rowT-slots * 12 (colT,w) = 1920 blocks (36 early-return)
  gemm_k<<<dim3(1920), 256, 0, stream>>>(xb, Wqb, bqb, Wkb, bkb, Wvb, bvb, pos,
                                         qf, kf, (void*)vf, NN, 0, 0);
  edge_attn<<<dim3(NN/4), 256, 0, stream>>>(cols, qf, kf, vf, y);
  // out: 8 * 20 * 4 = 640 blocks
  gemm_k<<<dim3(640), 256, 0, stream>>>(y, Wqb, bqb, Wkb, bkb, Wob, bob, pos,
                                        qf, kf, d_out, NN, 1, 1);
}

// Round 12
// 255.500 us; speedup vs baseline: 1.9875x; 1.0616x over previous
//
#include <hip/hip_runtime.h>
#include <hip/hip_bf16.h>

#define NN 20000
#define DEG 16
#define KD 512      // IN_DIM
#define OD 512      // OUT_DIM
#define NH 4
#define DH 128
#define DROPE 126

#define BM 128
#define BN 128
#define BK 64       // [128][64] tiles, XOR-swizzled chunks, for global_load_lds

typedef unsigned short u16;
typedef unsigned int u32;
typedef __attribute__((ext_vector_type(8))) short short8;
typedef __attribute__((ext_vector_type(4))) float f32x4;

__device__ __forceinline__ float b2f(u16 u){ return __uint_as_float((u32)u << 16); }
__device__ __forceinline__ u16 f2b(float f){
  u32 x = __float_as_uint(f);
  return (u16)((x + 0x7fffu + ((x >> 16) & 1u)) >> 16);   // RNE
}
__device__ __forceinline__ void up8(uint4 u, float* f){
  f[0]=__uint_as_float(u.x<<16); f[1]=__uint_as_float(u.x&0xffff0000u);
  f[2]=__uint_as_float(u.y<<16); f[3]=__uint_as_float(u.y&0xffff0000u);
  f[4]=__uint_as_float(u.z<<16); f[5]=__uint_as_float(u.z&0xffff0000u);
  f[6]=__uint_as_float(u.w<<16); f[7]=__uint_as_float(u.w&0xffff0000u);
}
__device__ __forceinline__ uint4 cvt8(const float* s){
  uint4 a = *(const uint4*)s;
  uint4 b = *(const uint4*)(s + 4);
  uint4 o;
  o.x = (u32)f2b(__uint_as_float(a.x)) | ((u32)f2b(__uint_as_float(a.y)) << 16);
  o.y = (u32)f2b(__uint_as_float(a.z)) | ((u32)f2b(__uint_as_float(a.w)) << 16);
  o.z = (u32)f2b(__uint_as_float(b.x)) | ((u32)f2b(__uint_as_float(b.y)) << 16);
  o.w = (u32)f2b(__uint_as_float(b.z)) | ((u32)f2b(__uint_as_float(b.w)) << 16);
  return o;
}

// async global->LDS, 16B per lane; LDS dest is wave-uniform base + lane*16
__device__ __forceinline__ void load_lds16(const u16* g, u16* l) {
  __builtin_amdgcn_global_load_lds(
      (const __attribute__((address_space(1))) void*)g,
      (__attribute__((address_space(3))) void*)l, 16, 0, 0);
}

// single fused f32->bf16 conversion pass: x (5000 blocks), W x4 (512), biases (1)
struct ConvJob {
  const float* x;  u16* xb;                  // NN*KD
  const float* w[4]; u16* wb[4];             // OD*KD each
  const float* b[4]; u16* bb[4];             // OD each
};
__global__ __launch_bounds__(256) void conv_all(ConvJob j) {
  const int b = blockIdx.x;
  if (b < 5000) {                            // x: 10.24M elems
    const int i8 = (b * 256 + threadIdx.x) * 8;
    *(uint4*)(j.xb + i8) = cvt8(j.x + i8);
  } else if (b < 5512) {                     // weights: 4 x 262144 elems
    const int t = b - 5000;
    const int wsel = t >> 7;                 // 128 blocks per weight
    const int i8 = ((t & 127) * 256 + threadIdx.x) * 8;
    *(uint4*)(j.wb[wsel] + i8) = cvt8(j.w[wsel] + i8);
  } else {                                   // biases: 4 x 512 elems in one block
    const int vsel = threadIdx.x >> 6;
    const int i8 = (threadIdx.x & 63) * 8;
    *(uint4*)(j.bb[vsel] + i8) = cvt8(j.b[vsel] + i8);
  }
}

// out[m][o] = sum_k A[m][k]*W[o][k] + bias[o]
// mode 0: q -> scale + rope -> o0 [N][H][DH] bf16
// mode 1: k -> rope -> o1 [N][H][DH] bf16
// mode 2: natural store to o2 [M][OD]  (f32 iff f32out, else bf16)
// BK=64 (8 K-iters) is the validated sweet spot: BK=32 + 2-pass epilogue at
// 8 blocks/CU regressed 15us (R11) — barrier amortization beats occupancy here.
// 1D grid, XCD-locality mapping: xcd = b&7 owns contiguous rowT set with all
// (colT,w) sub-blocks adjacent -> A-tile + W working set (~4.2MB) stays in L2.
__global__ __launch_bounds__(256, 4) void gemm_k(
    const u16* __restrict__ A,
    const u16* __restrict__ W0, const u16* __restrict__ B0,
    const u16* __restrict__ W1, const u16* __restrict__ B1,
    const u16* __restrict__ W2, const u16* __restrict__ B2,
    const float* __restrict__ pos,          // f32! bf16 pos loses 0.2 rad of RoPE angle
    u16* __restrict__ o0, u16* __restrict__ o1, void* __restrict__ o2,
    int M, int only2, int f32out)
{
  // union: staging (As 16KB + Bs 16KB) / epilogue repack (<=36.9KB)
  __shared__ __align__(16) char smem[36864];
  __shared__ float posS[BM*3];
  __shared__ float freqS[21];               // 10000^(-m/21), m=0..20
  u16* As = (u16*)smem;               // [128 rows][8 chunks], chunk XOR-swizzled
  u16* Bs = As + BM*BK;

  const int b = blockIdx.x;
  const int xcd = b & 7, rem = b >> 3;
  int rowT, colT, w;
  if (only2) {
    rowT = (rem >> 2)*8 + xcd; colT = rem & 3; w = 2;
  } else {
    rowT = (rem / 12)*8 + xcd; const int sub = rem % 12; colT = sub & 3; w = sub >> 2;
  }
  if (rowT*BM >= M) return;

  const int tid = threadIdx.x;
  const int wave = tid >> 6, lane = tid & 63;
  const int wr = wave >> 1, wc = wave & 1;
  const int lm = lane & 15, lq = lane >> 4;
  const u16* W  = (w == 0) ? W0 : ((w == 1) ? W1 : W2);
  const u16* Bi = (w == 0) ? B0 : ((w == 1) ? B1 : B2);
  const int mode = w;                 // uniform per block
  u16* outQK = (w == 0) ? o0 : o1;

  f32x4 acc[4][4];
  #pragma unroll
  for (int i = 0; i < 4; i++)
    #pragma unroll
    for (int jj = 0; jj < 4; jj++)
      acc[i][jj] = (f32x4){0.f, 0.f, 0.f, 0.f};

  if (mode < 2) {                     // stage pos + freq (covered by first barrier)
    if (tid < BM) {
      int gr = rowT*BM + tid; if (gr >= M) gr = M - 1;
      posS[tid*3+0] = pos[gr*3+0];
      posS[tid*3+1] = pos[gr*3+1];
      posS[tid*3+2] = pos[gr*3+2];
    }
    if (tid >= BM && tid < BM + 21)
      freqS[tid - BM] = __expf(-(float)(tid - BM) * 0.43858763676077064f);
  }

  for (int kt = 0; kt < KD; kt += BK) {
    // stage A/B: physical chunk c holds global (row=c>>3, seg=(c&7)^(row&7));
    // ds_read of (row,seg) -> chunk row*8 + (seg^(row&7)) -> banks spread 8-way.
    #pragma unroll
    for (int it = 0; it < 4; it++) {
      const int chunk = it*256 + wave*64 + lane;   // 0..1023
      const int row = chunk >> 3, gseg = (chunk & 7) ^ (row & 7);
      int gr = rowT*BM + row; if (gr >= M) gr = M - 1;
      load_lds16(A + (size_t)gr*KD + kt + gseg*8,
                 As + (size_t)(it*256 + wave*64)*8);
    }
    #pragma unroll
    for (int it = 0; it < 4; it++) {
      const int chunk = it*256 + wave*64 + lane;
      const int row = chunk >> 3, gseg = (chunk & 7) ^ (row & 7);
      load_lds16(W + (size_t)(colT*BN + row)*KD + kt + gseg*8,
                 Bs + (size_t)(it*256 + wave*64)*8);
    }
    __syncthreads();                  // drains vmcnt (global_load_lds) too
    #pragma unroll
    for (int kk = 0; kk < BK; kk += 32) {
      const int ks = kk >> 3;                      // 0 or 4
      short8 af[4], bfr[4];
      #pragma unroll
      for (int i = 0; i < 4; i++) {
        const int ra = wr*64 + i*16 + lm;
        af[i] = *(const short8*)(As + (size_t)(ra*8 + ((ks + lq) ^ (ra & 7)))*8);
      }
      #pragma unroll
      for (int i = 0; i < 4; i++) {
        const int rb = wc*64 + i*16 + lm;
        bfr[i] = *(const short8*)(Bs + (size_t)(rb*8 + ((ks + lq) ^ (rb & 7)))*8);
      }
      #pragma unroll
      for (int mi = 0; mi < 4; mi++)
        #pragma unroll
        for (int ni = 0; ni < 4; ni++)
          acc[mi][ni] = __builtin_amdgcn_mfma_f32_16x16x32_bf16(af[mi], bfr[ni], acc[mi][ni], 0, 0, 0);
    }
    __syncthreads();
  }

  float bvv[4];
  #pragma unroll
  for (int ni = 0; ni < 4; ni++)
    bvv[ni] = b2f(Bi[colT*BN + wc*64 + ni*16 + lm]);

  u16* Cs = (u16*)smem;   // tiles dead after final barrier

  if (mode == 2 && f32out) {
    // direct f32 stores (payload 64KB > LDS); 64B segments per lq-group
    #pragma unroll
    for (int mi = 0; mi < 4; mi++)
      #pragma unroll
      for (int ni = 0; ni < 4; ni++) {
        const int Cg = colT*BN + wc*64 + ni*16 + lm;
        #pragma unroll
        for (int r = 0; r < 4; r++) {
          const int grow = rowT*BM + wr*64 + mi*16 + lq*4 + r;
          if (grow < M) ((float*)o2)[(size_t)grow*OD + Cg] = acc[mi][ni][r] + bvv[ni];
        }
      }
    return;
  }

  if (mode == 2) {
    // natural bf16 via LDS repack: Cs layout [128][136]
    #pragma unroll
    for (int mi = 0; mi < 4; mi++)
      #pragma unroll
      for (int ni = 0; ni < 4; ni++) {
        const int cloc = wc*64 + ni*16 + lm;
        #pragma unroll
        for (int r = 0; r < 4; r++) {
          const int rloc = wr*64 + mi*16 + lq*4 + r;
          Cs[rloc*136 + cloc] = f2b(acc[mi][ni][r] + bvv[ni]);
        }
      }
    __syncthreads();
    #pragma unroll
    for (int pass = 0; pass < 8; pass++) {
      const int c2 = pass*256 + tid;          // 0..2047
      const int cc = c2 & 15, rloc = c2 >> 4; // 16 chunks of 8 cols x 128 rows
      const int grow = rowT*BM + rloc;
      if (grow < M) {
        uint4 v = *(const uint4*)(Cs + rloc*136 + cc*8);
        *(uint4*)((u16*)o2 + (size_t)grow*OD + colT*BN + cc*8) = v;
      }
    }
    return;
  }

  // modes 0/1: scale/rope then repack to head-major [N][4][128]
  // Cs layout: [rloc 128][h 4][dloc 36(pad)]
  #pragma unroll
  for (int mi = 0; mi < 4; mi++) {
    #pragma unroll
    for (int ni = 0; ni < 4; ni++) {
      const int cloc = wc*64 + ni*16 + lm;
      const int h = cloc & 3, dloc = cloc >> 2;
      const int d = colT*32 + dloc;
      #pragma unroll
      for (int r = 0; r < 4; r++) {
        const int rloc = wr*64 + mi*16 + lq*4 + r;
        float v = acc[mi][ni][r] + bvv[ni];
        if (mode == 0) v *= 0.08838834764831845f;   // 1/sqrt(128)
        const float partner = __shfl_xor(v, 4);     // rope pair: d ^ 1 == lane ^ 4
        float vr = v;
        if (d < DROPE) {
          const int pp = d / 42, rem2 = d - pp*42, m = rem2 >> 1, par = rem2 & 1;
          const float ang = posS[rloc*3 + pp] * freqS[m];
          float sn, cs; __sincosf(ang, &sn, &cs);
          vr = par ? (v*cs + partner*sn) : (v*cs - partner*sn);
        }
        Cs[rloc*144 + h*36 + dloc] = f2b(vr);
      }
    }
  }
  __syncthreads();
  #pragma unroll
  for (int pass = 0; pass < 8; pass++) {
    const int c2 = pass*256 + tid;              // 0..2047
    const int dd8 = c2 & 3, h = (c2 >> 2) & 3, rloc = c2 >> 4;
    const int grow = rowT*BM + rloc;
    if (grow < M) {
      uint2 a = *(const uint2*)(Cs + rloc*144 + h*36 + dd8*8);
      uint2 b2 = *(const uint2*)(Cs + rloc*144 + h*36 + dd8*8 + 4);
      *(uint4*)(outQK + ((size_t)grow*NH + h)*DH + colT*32 + dd8*8)
          = make_uint4(a.x, a.y, b2.x, b2.y);
    }
  }
}

// one wave per node. Coalesced per-neighbor row loads; lane l holds slice
// (h=l>>4, d=(l&15)*8) of q and k -> partial dot + h-group reduction.
// Plain (L1-allocating) loads: L1 coalesces the 4 lanes/line; nt-bypass
// quadrupled L2 requests and regressed (R9). At roofline: ~330MB compulsory
// per-XCD refill @ ~3.6TB/s fabric = ~90us (invariant across 3 designs).
__global__ __launch_bounds__(256, 3) void edge_attn(
    const int* __restrict__ cols, const u16* __restrict__ qf,
    const u16* __restrict__ kf, const u16* __restrict__ vf,
    u16* __restrict__ y)
{
  const int wave = threadIdx.x >> 6;
  const int lane = threadIdx.x & 63;
  const int n = blockIdx.x*4 + wave;
  const int j = lane >> 2, h = lane & 3;      // score layout
  const int col = cols[n*DEG + j];

  // own q slice (coalesced)
  const uint4 qall = *(const uint4*)(qf + (size_t)n*OD + lane*8);

  int cjs[16];
  #pragma unroll
  for (int jj = 0; jj < 16; jj++) cjs[jj] = __shfl(col, jj*4);

  // 16 coalesced k row loads (oldest first)
  uint4 kreg[16];
  #pragma unroll
  for (int jj = 0; jj < 16; jj++)
    kreg[jj] = *(const uint4*)(kf + (size_t)cjs[jj]*OD + lane*8);

  // 16 coalesced v row loads (stay in flight through the score phase)
  uint4 vreg[16];
  #pragma unroll
  for (int jj = 0; jj < 16; jj++)
    vreg[jj] = *(const uint4*)(vf + (size_t)cjs[jj]*OD + lane*8);

  float qa[8];
  up8(qall, qa);

  // scores
  float s = 0.f;
  #pragma unroll
  for (int jj = 0; jj < 16; jj++) {
    float ka[8];
    up8(kreg[jj], ka);
    float pr = qa[0]*ka[0] + qa[1]*ka[1] + qa[2]*ka[2] + qa[3]*ka[3]
             + qa[4]*ka[4] + qa[5]*ka[5] + qa[6]*ka[6] + qa[7]*ka[7];
    pr += __shfl_xor(pr, 1);
    pr += __shfl_xor(pr, 2);
    pr += __shfl_xor(pr, 4);
    pr += __shfl_xor(pr, 8);                 // all 16 lanes of h-group hold s[jj, hg]
    const float red = __shfl(pr, h*16);      // s[jj, h] from group h's lane 0
    s = (j == jj) ? red : s;
  }

  // softmax over j: lanes stride 4 share h; masks 4..32 never touch bits 0-1
  float mx = s;
  #pragma unroll
  for (int msk = 4; msk < 64; msk <<= 1) mx = fmaxf(mx, __shfl_xor(mx, msk));
  float p = expf(s - mx);
  float dn = p;
  #pragma unroll
  for (int msk = 4; msk < 64; msk <<= 1) dn += __shfl_xor(dn, msk);
  const float attn = p / dn;

  // y accumulate from prefetched v: lane owns natural cols c = lane*8..+7 (h = t&3)
  float ya[8];
  #pragma unroll
  for (int t = 0; t < 8; t++) ya[t] = 0.f;
  #pragma unroll
  for (int jj = 0; jj < 16; jj++) {
    const float a0 = __shfl(attn, jj*4+0);
    const float a1 = __shfl(attn, jj*4+1);
    const float a2 = __shfl(attn, jj*4+2);
    const float a3 = __shfl(attn, jj*4+3);
    float va[8];
    up8(vreg[jj], va);
    ya[0] += a0*va[0]; ya[1] += a1*va[1]; ya[2] += a2*va[2]; ya[3] += a3*va[3];
    ya[4] += a0*va[4]; ya[5] += a1*va[5]; ya[6] += a2*va[6]; ya[7] += a3*va[7];
  }
  u32 pk[4];
  #pragma unroll
  for (int t = 0; t < 4; t++)
    pk[t] = (u32)f2b(ya[2*t]) | ((u32)f2b(ya[2*t+1]) << 16);
  *(uint4*)(y + (size_t)n*OD + lane*8) = make_uint4(pk[0], pk[1], pk[2], pk[3]);
}

extern "C" void kernel_launch(void* const* d_in, const int* in_sizes, int n_in,
                              void* d_out, int out_size, void* d_ws, size_t ws_size,
                              hipStream_t stream) {
  (void)in_sizes; (void)n_in; (void)out_size; (void)ws_size;
  const float* x   = (const float*)d_in[0];
  const float* pos = (const float*)d_in[1];
  // d_in[2] = rows: sorted repeat(arange(N), DEG) — structure used implicitly
  const int* cols = (const int*)d_in[3];
  const float* Wq = (const float*)d_in[4];
  const float* bq = (const float*)d_in[5];
  const float* Wk = (const float*)d_in[6];
  const float* bk = (const float*)d_in[7];
  const float* Wv = (const float*)d_in[8];
  const float* bv = (const float*)d_in[9];
  const float* Wo = (const float*)d_in[10];
  const float* bo = (const float*)d_in[11];

  char* ws = (char*)d_ws;
  size_t off = 0;
  auto carve = [&](size_t bytes) { char* p = ws + off; off += (bytes + 15) & ~(size_t)15; return p; };
  u16* xb   = (u16*)carve((size_t)NN*KD*2);
  u16* Wqb  = (u16*)carve((size_t)OD*KD*2);
  u16* Wkb  = (u16*)carve((size_t)OD*KD*2);
  u16* Wvb  = (u16*)carve((size_t)OD*KD*2);
  u16* Wob  = (u16*)carve((size_t)OD*OD*2);
  u16* bqb  = (u16*)carve((size_t)OD*2);
  u16* bkb  = (u16*)carve((size_t)OD*2);
  u16* bvb  = (u16*)carve((size_t)OD*2);
  u16* bob  = (u16*)carve((size_t)OD*2);
  u16* qf   = (u16*)carve((size_t)NN*OD*2);
  u16* kf   = (u16*)carve((size_t)NN*OD*2);
  u16* vf   = (u16*)carve((size_t)NN*OD*2);
  u16* y    = (u16*)carve((size_t)NN*OD*2);

  ConvJob cj;
  cj.x = x; cj.xb = xb;
  cj.w[0]=Wq; cj.w[1]=Wk; cj.w[2]=Wv; cj.w[3]=Wo;
  cj.wb[0]=Wqb; cj.wb[1]=Wkb; cj.wb[2]=Wvb; cj.wb[3]=Wob;
  cj.b[0]=bq; cj.b[1]=bk; cj.b[2]=bv; cj.b[3]=bo;
  cj.bb[0]=bqb; cj.bb[1]=bkb; cj.bb[2]=bvb; cj.bb[3]=bob;
  conv_all<<<dim3(5513), 256, 0, stream>>>(cj);

  // QKV: 8 xcd * 20 rowT-slots * 12 (colT,w) = 1920 blocks (36 early-return)
  gemm_k<<<dim3(1920), 256, 0, stream>>>(xb, Wqb, bqb, Wkb, bkb, Wvb, bvb, pos,
                                         qf, kf, (void*)vf, NN, 0, 0);
  edge_attn<<<dim3(NN/4), 256, 0, stream>>>(cols, qf, kf, vf, y);
  // out: 8 * 20 * 4 = 640 blocks
  gemm_k<<<dim3(640), 256, 0, stream>>>(y, Wqb, bqb, Wkb, bkb, Wob, bob, pos,
                                        qf, kf, d_out, NN, 1, 1);
}